// Round 7
// baseline (663.813 us; speedup 1.0000x reference)
//
#include <hip/hip_runtime.h>
#include <hip/hip_bf16.h>
#include <cstdint>

#define TOKENS 8192
#define DIN 1024
#define DOUT 1024
#define NE 8

typedef __bf16 bf16;
typedef __attribute__((ext_vector_type(8))) __bf16 bf16x8;
typedef __attribute__((ext_vector_type(4))) float floatx4;

// async global->LDS, 16B per lane. LDS dest must be wave-uniform base + lane*16.
__device__ __forceinline__ void async16(const void* gptr, void* lptr) {
  __builtin_amdgcn_global_load_lds(
      (const __attribute__((address_space(1))) void*)gptr,
      (__attribute__((address_space(3))) void*)lptr,
      16, 0, 0);
}

// ---------------------------------------------------------------------------
// R13 prep: gate+trans re-fused (one launch fewer). Blocks [0,512) = gate
// (R11-verified: softmax + x -> fragment-major xbf). Blocks [512,2560) =
// w transpose with XCD-contiguous mapping: e = bt&7 (= XCD under %8
// round-robin) so each XCD transposes exactly one expert (4.2MB, L2-fits),
// and consecutive same-XCD blocks share the same 64 source rows.
// ---------------------------------------------------------------------------
__global__ __launch_bounds__(256) void prep_kernel(
    const float* __restrict__ x, const float* __restrict__ gw,
    const float* __restrict__ gb, float* __restrict__ g,
    bf16* __restrict__ xbf, const float* __restrict__ w,
    bf16* __restrict__ wt) {
  __shared__ __align__(16) float smem[NE * DIN];   // 32 KB
  __shared__ __align__(16) bf16 xtile[8][1032];    // 16.5 KB

  const int tid = threadIdx.x;
  if (blockIdx.x < 512) {
    const int bg = blockIdx.x;
#pragma unroll
    for (int k = 0; k < 8; ++k) {
      const int base = (k * 256 + tid) * 4;
      const floatx4 v = *(const floatx4*)(gw + base);
#pragma unroll
      for (int m = 0; m < 4; ++m) {
        const int j = base + m;
        smem[(j & 7) * DIN + (j >> 3)] = v[m];
      }
    }
    __syncthreads();

    const int lane = tid & 63;
    const int wave = tid >> 6;

#pragma unroll
    for (int h = 0; h < 2; ++h) {
#pragma unroll
      for (int tt = 0; tt < 2; ++tt) {
        const int tl = h * 8 + tt * 4 + wave;   // token-in-group 0..15
        const int t = bg * 16 + tl;
        const float* xr = x + (size_t)t * DIN;
        bf16* const xrow = &xtile[tl & 7][0];

        float acc[NE];
#pragma unroll
        for (int e = 0; e < NE; ++e) acc[e] = 0.f;

#pragma unroll
        for (int it = 0; it < 4; ++it) {
          const int i = it * 256 + lane * 4;
          const floatx4 xv = *(const floatx4*)(xr + i);
          union { bf16 b[4]; uint64_t u; } cv;
#pragma unroll
          for (int m = 0; m < 4; ++m) cv.b[m] = (bf16)xv[m];
          *(uint64_t*)(xrow + i) = cv.u;
#pragma unroll
          for (int e = 0; e < NE; ++e) {
            const floatx4 wv = *(const floatx4*)(smem + e * DIN + i);
            acc[e] += xv[0] * wv[0] + xv[1] * wv[1] + xv[2] * wv[2] + xv[3] * wv[3];
          }
        }
#pragma unroll
        for (int e = 0; e < NE; ++e)
#pragma unroll
          for (int off = 32; off > 0; off >>= 1)
            acc[e] += __shfl_xor(acc[e], off, 64);

        float lg[NE];
        float mx = -3.0e38f;
#pragma unroll
        for (int e = 0; e < NE; ++e) { lg[e] = acc[e] + gb[e]; mx = fmaxf(mx, lg[e]); }
        float s = 0.f;
#pragma unroll
        for (int e = 0; e < NE; ++e) { lg[e] = __expf(lg[e] - mx); s += lg[e]; }
        const float inv = 1.f / s;
        if (lane == 0) {
          floatx4 o0, o1;
#pragma unroll
          for (int e = 0; e < 4; ++e) { o0[e] = lg[e] * inv; o1[e] = lg[e + 4] * inv; }
          *(floatx4*)(g + (size_t)t * NE) = o0;
          *(floatx4*)(g + (size_t)t * NE + 4) = o1;
        }
      }
      __syncthreads();
      // write out half h in fragment-major order: 4 passes x 256 units of 16B
#pragma unroll
      for (int p = 0; p < 4; ++p) {
        const int u = p * 256 + tid;           // [0,1024)
        const int lr3 = u & 7;
        const int lq = (u >> 3) & 3;
        const int kkv = (u >> 5) & 1;
        const int kt = u >> 6;                 // [0,16)
        const bf16x8 v = *(const bf16x8*)(&xtile[lr3][kt * 64 + kkv * 32 + lq * 8]);
        const size_t off = (size_t)bg * 16384 +
            (size_t)((((kt * 2 + kkv) * 4 + lq) * 16) + h * 8 + lr3) * 8;
        *(bf16x8*)(xbf + off) = v;
      }
      __syncthreads();
    }
  } else {
    float (*tile)[65] = (float(*)[65])smem;    // 16.6 KB of smem
    const int bt = blockIdx.x - 512;
    const int e = bt & 7;                      // = XCD under %8 round-robin
    const int j = bt >> 3;
    const int i0 = (j >> 4) * 64;
    const int o0 = (j & 15) * 64;              // consecutive same-XCD blocks
    const int c4 = (tid & 15) * 4;             //   sweep o0 (share src rows)
    const int r = tid >> 4;

    const float* src = w + ((size_t)e * DIN + i0) * DOUT + o0;
#pragma unroll
    for (int rr = r; rr < 64; rr += 16) {
      const floatx4 v = *(const floatx4*)(src + (size_t)rr * DOUT + c4);
      tile[rr][c4] = v[0]; tile[rr][c4 + 1] = v[1];
      tile[rr][c4 + 2] = v[2]; tile[rr][c4 + 3] = v[3];
    }
    __syncthreads();
    bf16* dst = wt + ((size_t)e * DOUT + o0) * DIN + i0;
#pragma unroll
    for (int rr = r; rr < 64; rr += 16) {
      union { bf16 b[4]; uint64_t u; } cv;
#pragma unroll
      for (int jj = 0; jj < 4; ++jj) cv.b[jj] = (bf16)tile[c4 + jj][rr];
      *(uint64_t*)(dst + (size_t)rr * DIN + c4) = cv.u;
    }
  }
}

// ---------------------------------------------------------------------------
// Fused MoE GEMM, R13: depth-3 counted-vmcnt pipeline, 4 B-buffers (64KB).
// R12 post-mortem: its vmcnt(0) at body top drained loads issued one
// MFMA-cluster earlier (SHORTER flight than R8). Fix = counted wait (T4):
// body T: [issue avv(T+1)] [vmcnt(12): FIFO-drains exactly avv(T)+stage(T),
// leaves stage(T+1..T+3)+avv(T+1) in flight] [s_barrier] [stage B(T+3) —
// its buffer's readers all passed the barrier] [g-loads at TOFF==0]
// [ds_read bv] [32 MFMA]. Each B-stage flies ~3 bodies (>=2500cyc >> 900cyc
// HBM). TOFF==1 uses vmcnt(28) to cover the 16 g-loads in its window.
// Compiler's own dependency waits remain the correctness net for reg loads.
// A direct-to-register from fragment-major xbf (verified R11); swizzle/fold/
// C-write identical to verified R8-R12.
// ---------------------------------------------------------------------------
template <int TOFF>
__device__ __forceinline__ void gemm_body(
    int e, bf16* Bs, const bf16* abase, const bf16* bgp, const float* g,
    bf16x8 (&avv)[2][2][4], float (&gcur)[4][4],
    floatx4 (&accE)[4][4], floatx4 (&accF)[4][4],
    int tid, int tok0, int lq, int kx, int wn, int lr) {
  constexpr int PAR = TOFF & 1;
  const int T = e * 16 + TOFF;

  // 1) issue A-frags for T+1 into parity PAR^1 (register dest)
  if (T + 1 < 128) {
    const int ktn = (T + 1) & 15;
#pragma unroll
    for (int kk = 0; kk < 2; ++kk)
#pragma unroll
      for (int im = 0; im < 4; ++im)
        avv[PAR ^ 1][kk][im] = *(const bf16x8*)(abase + (size_t)im * 16384 +
                                                (ktn * 2 + kk) * 512);
  }
  // 2) counted wait: guarantees stage(T) resident, keeps newer loads in flight
  if constexpr (TOFF == 1)
    asm volatile("s_waitcnt vmcnt(28)" ::: "memory");
  else
    asm volatile("s_waitcnt vmcnt(12)" ::: "memory");
  __builtin_amdgcn_s_barrier();
  asm volatile("" ::: "memory");
  // 3) stage B(T+3) into buf (TOFF+3)&3 — readers of that buf passed barrier
  if (T + 3 < 128) {
    const int ts = T + 3;
    const bf16* const bsrc =
        bgp + ((size_t)(ts >> 4) << 20) + (size_t)(ts & 15) * 64;
    bf16* const blp = Bs + ((TOFF + 3) & 3) * 8192 + tid * 8;
#pragma unroll
    for (int j = 0; j < 4; ++j)
      async16(bsrc + (size_t)(32 * j) * DIN, blp + j * 2048);
  }
  // 4) gate weights for this expert (consumed at TOFF==15, flight 15 bodies)
  if constexpr (TOFF == 0) {
#pragma unroll
    for (int im = 0; im < 4; ++im)
#pragma unroll
      for (int r = 0; r < 4; ++r)
        gcur[im][r] = g[(size_t)(tok0 + im * 16 + lq * 4 + r) * NE + e];
  }
  // 5) B fragments from buf TOFF&3
  const bf16* const Bb = Bs + (TOFF & 3) * 8192;
  bf16x8 bv[2][4];
#pragma unroll
  for (int kk = 0; kk < 2; ++kk) {
    const int kg = ((kk * 4 + lq) ^ kx) << 3;
#pragma unroll
    for (int in = 0; in < 4; ++in)
      bv[kk][in] = *(const bf16x8*)(Bb + (wn * 64 + in * 16 + lr) * 64 + kg);
  }
  // 6) MFMA
  __builtin_amdgcn_s_setprio(1);
#pragma unroll
  for (int kk = 0; kk < 2; ++kk)
#pragma unroll
    for (int im = 0; im < 4; ++im)
#pragma unroll
      for (int in = 0; in < 4; ++in)
        accE[im][in] = __builtin_amdgcn_mfma_f32_16x16x32_bf16(
            avv[PAR][kk][im], bv[kk][in], accE[im][in], 0, 0, 0);
  __builtin_amdgcn_s_setprio(0);
  // 7) expert-boundary fold
  if constexpr (TOFF == 15) {
#pragma unroll
    for (int im = 0; im < 4; ++im)
#pragma unroll
      for (int in = 0; in < 4; ++in)
#pragma unroll
        for (int r = 0; r < 4; ++r) {
          accF[im][in][r] += gcur[im][r] * accE[im][in][r];
          accE[im][in][r] = 0.f;
        }
  }
}

__global__ __launch_bounds__(256, 2) void moe_gemm(
    const bf16* __restrict__ xbf, const bf16* __restrict__ wt,
    const float* __restrict__ g, float* __restrict__ out) {
  __shared__ __align__(16) bf16 Bs[4 * 128 * 64];  // 64KB, 4 buffers

  const int tid = threadIdx.x;
  // XCD swizzle (verified R7): per-XCD chunk = 16 bm x 4 bn.
  const int c = blockIdx.x & 7;
  const int jj = blockIdx.x >> 3;
  const int bm = (c >> 1) * 16 + (jj & 15);   // 0..63
  const int bn = (c & 1) * 4 + (jj >> 4);     // 0..7
  const int lane = tid & 63;
  const int wave = tid >> 6;
  const int wm = wave >> 1, wn = wave & 1;
  const int lr = lane & 15, lq = lane >> 4;

  // B staging (verified R8): srow 0..31 (+32/pass), swizzled col.
  const int srow = tid >> 3;
  const int scol = (((tid & 7) ^ (srow & 7)) << 3);
  const int kx = lr & 7;

  const bf16* const bgp = wt + (size_t)(bn * 128 + srow) * DIN + scol;
  const bf16* const abase = xbf + (size_t)(bm * 8 + wm * 4) * 16384 + lane * 8;

  const floatx4 fzero = {0.f, 0.f, 0.f, 0.f};
  floatx4 accF[4][4], accE[4][4];
#pragma unroll
  for (int im = 0; im < 4; ++im)
#pragma unroll
    for (int in = 0; in < 4; ++in) { accF[im][in] = fzero; accE[im][in] = fzero; }

  const int tok0 = bm * 128 + wm * 64;

  bf16x8 avv[2][2][4];
  float gcur[4][4];

  // prologue: stage B(0..2) -> buf0..2; avv(0) -> parity 0
#pragma unroll
  for (int s = 0; s < 3; ++s) {
    const bf16* const bsrc = bgp + (size_t)s * 64;
    bf16* const blp = Bs + s * 8192 + tid * 8;
#pragma unroll
    for (int j = 0; j < 4; ++j)
      async16(bsrc + (size_t)(32 * j) * DIN, blp + j * 2048);
  }
#pragma unroll
  for (int kk = 0; kk < 2; ++kk)
#pragma unroll
    for (int im = 0; im < 4; ++im)
      avv[0][kk][im] = *(const bf16x8*)(abase + (size_t)im * 16384 + kk * 512);

  for (int e = 0; e < NE; ++e) {
    gemm_body<0>(e, Bs, abase, bgp, g, avv, gcur, accE, accF, tid, tok0, lq, kx, wn, lr);
    gemm_body<1>(e, Bs, abase, bgp, g, avv, gcur, accE, accF, tid, tok0, lq, kx, wn, lr);
    gemm_body<2>(e, Bs, abase, bgp, g, avv, gcur, accE, accF, tid, tok0, lq, kx, wn, lr);
    gemm_body<3>(e, Bs, abase, bgp, g, avv, gcur, accE, accF, tid, tok0, lq, kx, wn, lr);
    gemm_body<4>(e, Bs, abase, bgp, g, avv, gcur, accE, accF, tid, tok0, lq, kx, wn, lr);
    gemm_body<5>(e, Bs, abase, bgp, g, avv, gcur, accE, accF, tid, tok0, lq, kx, wn, lr);
    gemm_body<6>(e, Bs, abase, bgp, g, avv, gcur, accE, accF, tid, tok0, lq, kx, wn, lr);
    gemm_body<7>(e, Bs, abase, bgp, g, avv, gcur, accE, accF, tid, tok0, lq, kx, wn, lr);
    gemm_body<8>(e, Bs, abase, bgp, g, avv, gcur, accE, accF, tid, tok0, lq, kx, wn, lr);
    gemm_body<9>(e, Bs, abase, bgp, g, avv, gcur, accE, accF, tid, tok0, lq, kx, wn, lr);
    gemm_body<10>(e, Bs, abase, bgp, g, avv, gcur, accE, accF, tid, tok0, lq, kx, wn, lr);
    gemm_body<11>(e, Bs, abase, bgp, g, avv, gcur, accE, accF, tid, tok0, lq, kx, wn, lr);
    gemm_body<12>(e, Bs, abase, bgp, g, avv, gcur, accE, accF, tid, tok0, lq, kx, wn, lr);
    gemm_body<13>(e, Bs, abase, bgp, g, avv, gcur, accE, accF, tid, tok0, lq, kx, wn, lr);
    gemm_body<14>(e, Bs, abase, bgp, g, avv, gcur, accE, accF, tid, tok0, lq, kx, wn, lr);
    gemm_body<15>(e, Bs, abase, bgp, g, avv, gcur, accE, accF, tid, tok0, lq, kx, wn, lr);
  }

#pragma unroll
  for (int im = 0; im < 4; ++im)
#pragma unroll
    for (int in = 0; in < 4; ++in) {
      const int col = bn * 128 + wn * 64 + in * 16 + lr;
#pragma unroll
      for (int r = 0; r < 4; ++r)
        out[(size_t)(tok0 + im * 16 + lq * 4 + r) * DOUT + col] =
            accF[im][in][r];
    }
}

// ---------------------------------------------------------------------------
extern "C" void kernel_launch(void* const* d_in, const int* in_sizes, int n_in,
                              void* d_out, int out_size, void* d_ws,
                              size_t ws_size, hipStream_t stream) {
  const float* x  = (const float*)d_in[0];
  const float* gw = (const float*)d_in[1];
  const float* gb = (const float*)d_in[2];
  const float* w  = (const float*)d_in[3];
  float* out = (float*)d_out;

  char* ws = (char*)d_ws;
  float* g   = (float*)ws;
  bf16* xbf  = (bf16*)(ws + 262144);
  bf16* wt   = (bf16*)(ws + 262144 + (size_t)TOKENS * DIN * 2);

  prep_kernel<<<2560, 256, 0, stream>>>(x, gw, gb, g, xbf, w, wt);
  moe_gemm<<<512, 256, 0, stream>>>(xbf, wt, g, out);
}

// Round 8
// 259.344 us; speedup vs baseline: 2.5596x; 2.5596x over previous
//
#include <hip/hip_runtime.h>
#include <hip/hip_bf16.h>
#include <cstdint>

#define TOKENS 8192
#define DIN 1024
#define DOUT 1024
#define NE 8

typedef __bf16 bf16;
typedef __attribute__((ext_vector_type(8))) __bf16 bf16x8;
typedef __attribute__((ext_vector_type(4))) float floatx4;

// async global->LDS, 16B per lane. LDS dest must be wave-uniform base + lane*16.
__device__ __forceinline__ void async16(const void* gptr, void* lptr) {
  __builtin_amdgcn_global_load_lds(
      (const __attribute__((address_space(1))) void*)gptr,
      (__attribute__((address_space(3))) void*)lptr,
      16, 0, 0);
}

// ---------------------------------------------------------------------------
// Prep (byte-identical to R13's passed version). Blocks [0,512) = gate
// (softmax + x -> fragment-major xbf). Blocks [512,2560) = w transpose,
// XCD-contiguous mapping (e = bt&7 = XCD under %8 round-robin).
// ---------------------------------------------------------------------------
__global__ __launch_bounds__(256) void prep_kernel(
    const float* __restrict__ x, const float* __restrict__ gw,
    const float* __restrict__ gb, float* __restrict__ g,
    bf16* __restrict__ xbf, const float* __restrict__ w,
    bf16* __restrict__ wt) {
  __shared__ __align__(16) float smem[NE * DIN];   // 32 KB
  __shared__ __align__(16) bf16 xtile[8][1032];    // 16.5 KB

  const int tid = threadIdx.x;
  if (blockIdx.x < 512) {
    const int bg = blockIdx.x;
#pragma unroll
    for (int k = 0; k < 8; ++k) {
      const int base = (k * 256 + tid) * 4;
      const floatx4 v = *(const floatx4*)(gw + base);
#pragma unroll
      for (int m = 0; m < 4; ++m) {
        const int j = base + m;
        smem[(j & 7) * DIN + (j >> 3)] = v[m];
      }
    }
    __syncthreads();

    const int lane = tid & 63;
    const int wave = tid >> 6;

#pragma unroll
    for (int h = 0; h < 2; ++h) {
#pragma unroll
      for (int tt = 0; tt < 2; ++tt) {
        const int tl = h * 8 + tt * 4 + wave;   // token-in-group 0..15
        const int t = bg * 16 + tl;
        const float* xr = x + (size_t)t * DIN;
        bf16* const xrow = &xtile[tl & 7][0];

        float acc[NE];
#pragma unroll
        for (int e = 0; e < NE; ++e) acc[e] = 0.f;

#pragma unroll
        for (int it = 0; it < 4; ++it) {
          const int i = it * 256 + lane * 4;
          const floatx4 xv = *(const floatx4*)(xr + i);
          union { bf16 b[4]; uint64_t u; } cv;
#pragma unroll
          for (int m = 0; m < 4; ++m) cv.b[m] = (bf16)xv[m];
          *(uint64_t*)(xrow + i) = cv.u;
#pragma unroll
          for (int e = 0; e < NE; ++e) {
            const floatx4 wv = *(const floatx4*)(smem + e * DIN + i);
            acc[e] += xv[0] * wv[0] + xv[1] * wv[1] + xv[2] * wv[2] + xv[3] * wv[3];
          }
        }
#pragma unroll
        for (int e = 0; e < NE; ++e)
#pragma unroll
          for (int off = 32; off > 0; off >>= 1)
            acc[e] += __shfl_xor(acc[e], off, 64);

        float lg[NE];
        float mx = -3.0e38f;
#pragma unroll
        for (int e = 0; e < NE; ++e) { lg[e] = acc[e] + gb[e]; mx = fmaxf(mx, lg[e]); }
        float s = 0.f;
#pragma unroll
        for (int e = 0; e < NE; ++e) { lg[e] = __expf(lg[e] - mx); s += lg[e]; }
        const float inv = 1.f / s;
        if (lane == 0) {
          floatx4 o0, o1;
#pragma unroll
          for (int e = 0; e < 4; ++e) { o0[e] = lg[e] * inv; o1[e] = lg[e + 4] * inv; }
          *(floatx4*)(g + (size_t)t * NE) = o0;
          *(floatx4*)(g + (size_t)t * NE + 4) = o1;
        }
      }
      __syncthreads();
      // write out half h in fragment-major order: 4 passes x 256 units of 16B
#pragma unroll
      for (int p = 0; p < 4; ++p) {
        const int u = p * 256 + tid;           // [0,1024)
        const int lr3 = u & 7;
        const int lq = (u >> 3) & 3;
        const int kkv = (u >> 5) & 1;
        const int kt = u >> 6;                 // [0,16)
        const bf16x8 v = *(const bf16x8*)(&xtile[lr3][kt * 64 + kkv * 32 + lq * 8]);
        const size_t off = (size_t)bg * 16384 +
            (size_t)((((kt * 2 + kkv) * 4 + lq) * 16) + h * 8 + lr3) * 8;
        *(bf16x8*)(xbf + off) = v;
      }
      __syncthreads();
    }
  } else {
    float (*tile)[65] = (float(*)[65])smem;    // 16.6 KB of smem
    const int bt = blockIdx.x - 512;
    const int e = bt & 7;                      // = XCD under %8 round-robin
    const int j = bt >> 3;
    const int i0 = (j >> 4) * 64;
    const int o0 = (j & 15) * 64;
    const int c4 = (tid & 15) * 4;
    const int r = tid >> 4;

    const float* src = w + ((size_t)e * DIN + i0) * DOUT + o0;
#pragma unroll
    for (int rr = r; rr < 64; rr += 16) {
      const floatx4 v = *(const floatx4*)(src + (size_t)rr * DOUT + c4);
      tile[rr][c4] = v[0]; tile[rr][c4 + 1] = v[1];
      tile[rr][c4 + 2] = v[2]; tile[rr][c4 + 3] = v[3];
    }
    __syncthreads();
    bf16* dst = wt + ((size_t)e * DOUT + o0) * DIN + i0;
#pragma unroll
    for (int rr = r; rr < 64; rr += 16) {
      union { bf16 b[4]; uint64_t u; } cv;
#pragma unroll
      for (int jj = 0; jj < 4; ++jj) cv.b[jj] = (bf16)tile[c4 + jj][rr];
      *(uint64_t*)(dst + (size_t)rr * DIN + c4) = cv.u;
    }
  }
}

// ---------------------------------------------------------------------------
// Fused MoE GEMM, R14: depth-2 counted-vmcnt (register envelope of the
// verified 135-139us kernels; R13's depth-3 spilled: WRITE 206MB=scratch).
// FIFO math: steady-state outstanding at body top = stage(T)[4, oldest] +
// avv(T+1)[8]  =>  s_waitcnt vmcnt(8) retires exactly stage(T), keeps the
// rest in flight. Body: vmcnt(8); s_barrier (raw — no drain); [g-loads at
// expert start, BEFORE stage in FIFO so uniform vmcnt(8) still works];
// stage(T+1) -> buf (T+1)&1 (readers passed barrier); ds_read bv(T);
// 32 MFMA avv[P]; issue avv(T+2) into parity P AFTER its consumer (no WAR
// rename); [fold at expert end]. sched_barrier(0) pins FIFO order.
// Traced bodies 0,1,16,17,127: vmcnt(8) always drains exactly through stage.
// ---------------------------------------------------------------------------
template <int P>
__device__ __forceinline__ void body(
    int T, bf16* BsAll, const bf16* abase, const bf16* bgp, const float* g,
    bf16x8 (&avv)[2][2][4], float (&gcur)[4][4],
    floatx4 (&accE)[4][4], floatx4 (&accF)[4][4],
    int tid, int tok0, int lq, int kx, int wn, int lr) {
  asm volatile("s_waitcnt vmcnt(8)" ::: "memory");
  __builtin_amdgcn_s_barrier();
  __builtin_amdgcn_sched_barrier(0);

  // gate weights for this expert (FIFO position: before stage)
  if ((T & 15) == 0) {
    const int e = T >> 4;
#pragma unroll
    for (int im = 0; im < 4; ++im)
#pragma unroll
      for (int r = 0; r < 4; ++r)
        gcur[im][r] = g[(size_t)(tok0 + im * 16 + lq * 4 + r) * NE + e];
    __builtin_amdgcn_sched_barrier(0);
  }

  // stage B(T+1) into the other buffer
  const int t1 = T + 1;
  if (t1 < 128) {
    const bf16* const bsrc =
        bgp + ((size_t)(t1 >> 4) << 20) + (size_t)(t1 & 15) * 64;
    bf16* const blp = BsAll + (t1 & 1) * 8192 + tid * 8;
#pragma unroll
    for (int j = 0; j < 4; ++j)
      async16(bsrc + (size_t)(32 * j) * DIN, blp + j * 2048);
  }
  __builtin_amdgcn_sched_barrier(0);

  // B fragments from buf T&1
  const bf16* const Bb = BsAll + (T & 1) * 8192;
  bf16x8 bv[2][4];
#pragma unroll
  for (int kk = 0; kk < 2; ++kk) {
    const int kg = ((kk * 4 + lq) ^ kx) << 3;
#pragma unroll
    for (int in = 0; in < 4; ++in)
      bv[kk][in] = *(const bf16x8*)(Bb + (wn * 64 + in * 16 + lr) * 64 + kg);
  }

  __builtin_amdgcn_s_setprio(1);
#pragma unroll
  for (int kk = 0; kk < 2; ++kk)
#pragma unroll
    for (int im = 0; im < 4; ++im)
#pragma unroll
      for (int in = 0; in < 4; ++in)
        accE[im][in] = __builtin_amdgcn_mfma_f32_16x16x32_bf16(
            avv[P][kk][im], bv[kk][in], accE[im][in], 0, 0, 0);
  __builtin_amdgcn_s_setprio(0);

  // issue A-frags for T+2 into parity P (its consumer just ran — no WAR)
  const int t2 = T + 2;
  if (t2 < 128) {
    const int kt2 = t2 & 15;
#pragma unroll
    for (int kk = 0; kk < 2; ++kk)
#pragma unroll
      for (int im = 0; im < 4; ++im)
        avv[P][kk][im] = *(const bf16x8*)(abase + (size_t)im * 16384 +
                                          (kt2 * 2 + kk) * 512);
  }
  __builtin_amdgcn_sched_barrier(0);

  // expert-boundary fold
  if ((T & 15) == 15) {
#pragma unroll
    for (int im = 0; im < 4; ++im)
#pragma unroll
      for (int in = 0; in < 4; ++in)
#pragma unroll
        for (int r = 0; r < 4; ++r) {
          accF[im][in][r] += gcur[im][r] * accE[im][in][r];
          accE[im][in][r] = 0.f;
        }
  }
}

__global__ __launch_bounds__(256, 2) void moe_gemm(
    const bf16* __restrict__ xbf, const bf16* __restrict__ wt,
    const float* __restrict__ g, float* __restrict__ out) {
  __shared__ __align__(16) bf16 Bs[2 * 128 * 64];  // 2 x 16KB

  const int tid = threadIdx.x;
  // XCD swizzle (verified R7): per-XCD chunk = 16 bm x 4 bn.
  const int c = blockIdx.x & 7;
  const int jj = blockIdx.x >> 3;
  const int bm = (c >> 1) * 16 + (jj & 15);   // 0..63
  const int bn = (c & 1) * 4 + (jj >> 4);     // 0..7
  const int lane = tid & 63;
  const int wave = tid >> 6;
  const int wm = wave >> 1, wn = wave & 1;
  const int lr = lane & 15, lq = lane >> 4;

  // B staging (verified R8): srow 0..31 (+32/pass), swizzled col.
  const int srow = tid >> 3;
  const int scol = (((tid & 7) ^ (srow & 7)) << 3);
  const int kx = lr & 7;

  const bf16* const bgp = wt + (size_t)(bn * 128 + srow) * DIN + scol;
  const bf16* const abase = xbf + (size_t)(bm * 8 + wm * 4) * 16384 + lane * 8;

  const floatx4 fzero = {0.f, 0.f, 0.f, 0.f};
  floatx4 accF[4][4], accE[4][4];
#pragma unroll
  for (int im = 0; im < 4; ++im)
#pragma unroll
    for (int in = 0; in < 4; ++in) { accF[im][in] = fzero; accE[im][in] = fzero; }

  const int tok0 = bm * 128 + wm * 64;

  bf16x8 avv[2][2][4];
  float gcur[4][4];

  // prologue FIFO order: avv(0) [8] ; stage(0) [4] ; avv(1) [8]
  // body0's vmcnt(8) retires avv(0)+stage(0), leaves avv(1) in flight.
#pragma unroll
  for (int kk = 0; kk < 2; ++kk)
#pragma unroll
    for (int im = 0; im < 4; ++im)
      avv[0][kk][im] = *(const bf16x8*)(abase + (size_t)im * 16384 + kk * 512);
  __builtin_amdgcn_sched_barrier(0);
  {
    bf16* const blp = Bs + tid * 8;
#pragma unroll
    for (int j = 0; j < 4; ++j)
      async16(bgp + (size_t)(32 * j) * DIN, blp + j * 2048);
  }
  __builtin_amdgcn_sched_barrier(0);
#pragma unroll
  for (int kk = 0; kk < 2; ++kk)
#pragma unroll
    for (int im = 0; im < 4; ++im)
      avv[1][kk][im] = *(const bf16x8*)(abase + (size_t)im * 16384 +
                                        (1 * 2 + kk) * 512);
  __builtin_amdgcn_sched_barrier(0);

  for (int t = 0; t < 128; t += 2) {
    body<0>(t, Bs, abase, bgp, g, avv, gcur, accE, accF,
            tid, tok0, lq, kx, wn, lr);
    body<1>(t + 1, Bs, abase, bgp, g, avv, gcur, accE, accF,
            tid, tok0, lq, kx, wn, lr);
  }

#pragma unroll
  for (int im = 0; im < 4; ++im)
#pragma unroll
    for (int in = 0; in < 4; ++in) {
      const int col = bn * 128 + wn * 64 + in * 16 + lr;
#pragma unroll
      for (int r = 0; r < 4; ++r)
        out[(size_t)(tok0 + im * 16 + lq * 4 + r) * DOUT + col] =
            accF[im][in][r];
    }
}

// ---------------------------------------------------------------------------
extern "C" void kernel_launch(void* const* d_in, const int* in_sizes, int n_in,
                              void* d_out, int out_size, void* d_ws,
                              size_t ws_size, hipStream_t stream) {
  const float* x  = (const float*)d_in[0];
  const float* gw = (const float*)d_in[1];
  const float* gb = (const float*)d_in[2];
  const float* w  = (const float*)d_in[3];
  float* out = (float*)d_out;

  char* ws = (char*)d_ws;
  float* g   = (float*)ws;
  bf16* xbf  = (bf16*)(ws + 262144);
  bf16* wt   = (bf16*)(ws + 262144 + (size_t)TOKENS * DIN * 2);

  prep_kernel<<<2560, 256, 0, stream>>>(x, gw, gb, g, xbf, w, wt);
  moe_gemm<<<512, 256, 0, stream>>>(xbf, wt, g, out);
}

// Round 9
// 235.823 us; speedup vs baseline: 2.8149x; 1.0997x over previous
//
#include <hip/hip_runtime.h>
#include <hip/hip_bf16.h>
#include <cstdint>

#define TOKENS 8192
#define DIN 1024
#define DOUT 1024
#define NE 8

typedef __bf16 bf16;
typedef __attribute__((ext_vector_type(8))) __bf16 bf16x8;
typedef __attribute__((ext_vector_type(4))) float floatx4;
typedef __attribute__((ext_vector_type(2))) float floatx2;

// async global->LDS, 16B per lane. LDS dest must be wave-uniform base + lane*16.
__device__ __forceinline__ void async16(const void* gptr, void* lptr) {
  __builtin_amdgcn_global_load_lds(
      (const __attribute__((address_space(1))) void*)gptr,
      (__attribute__((address_space(3))) void*)lptr,
      16, 0, 0);
}

// ---------------------------------------------------------------------------
// R15 gate (R1/R7-verified logic): gate softmax + x -> bf16 ROW-MAJOR xb,
// written directly from registers (no xtile LDS, no writeout passes).
// LDS = 32 KB gws only -> 5 blocks/CU capacity (2 resident needed).
// ---------------------------------------------------------------------------
__global__ __launch_bounds__(256) void gate_kernel(
    const float* __restrict__ x, const float* __restrict__ gw,
    const float* __restrict__ gb, float* __restrict__ g,
    bf16* __restrict__ xb) {
  __shared__ __align__(16) float gws[NE * DIN];  // 32 KB, gw transposed

  const int tid = threadIdx.x;
#pragma unroll
  for (int k = 0; k < 8; ++k) {
    const int base = (k * 256 + tid) * 4;
    const floatx4 v = *(const floatx4*)(gw + base);
#pragma unroll
    for (int m = 0; m < 4; ++m) {
      const int j = base + m;
      gws[(j & 7) * DIN + (j >> 3)] = v[m];
    }
  }
  __syncthreads();

  const int lane = tid & 63;
  const int wave = tid >> 6;
#pragma unroll
  for (int tt = 0; tt < 4; ++tt) {
    const int t = blockIdx.x * 16 + wave * 4 + tt;
    const float* xr = x + (size_t)t * DIN;
    bf16* xbr = xb + (size_t)t * DIN;

    float acc[NE];
#pragma unroll
    for (int e = 0; e < NE; ++e) acc[e] = 0.f;

#pragma unroll
    for (int it = 0; it < 4; ++it) {
      const int i = it * 256 + lane * 4;
      const floatx4 xv = *(const floatx4*)(xr + i);
      union { bf16 b[4]; uint64_t u; } cv;
#pragma unroll
      for (int m = 0; m < 4; ++m) cv.b[m] = (bf16)xv[m];
      *(uint64_t*)(xbr + i) = cv.u;
#pragma unroll
      for (int e = 0; e < NE; ++e) {
        const floatx4 wv = *(const floatx4*)(gws + e * DIN + i);
        acc[e] += xv[0] * wv[0] + xv[1] * wv[1] + xv[2] * wv[2] + xv[3] * wv[3];
      }
    }
#pragma unroll
    for (int e = 0; e < NE; ++e)
#pragma unroll
      for (int off = 32; off > 0; off >>= 1)
        acc[e] += __shfl_xor(acc[e], off, 64);

    float lg[NE];
    float mx = -3.0e38f;
#pragma unroll
    for (int e = 0; e < NE; ++e) { lg[e] = acc[e] + gb[e]; mx = fmaxf(mx, lg[e]); }
    float s = 0.f;
#pragma unroll
    for (int e = 0; e < NE; ++e) { lg[e] = __expf(lg[e] - mx); s += lg[e]; }
    const float inv = 1.f / s;
    if (lane == 0) {
      floatx4 o0, o1;
#pragma unroll
      for (int e = 0; e < 4; ++e) { o0[e] = lg[e] * inv; o1[e] = lg[e + 4] * inv; }
      *(floatx4*)(g + (size_t)t * NE) = o0;
      *(floatx4*)(g + (size_t)t * NE + 4) = o1;
    }
  }
}

// ---------------------------------------------------------------------------
// R15 trans: separate kernel so LDS = 16.6 KB -> 9 blocks/CU (the fused prep
// reserved 48.5 KB for trans blocks too -> 3/CU, serializing 2560 blocks).
// XCD-contiguous mapping: e = bt&7 (= XCD under %8 round-robin), consecutive
// same-XCD blocks sweep o0 (share source rows in that XCD's L2).
// ---------------------------------------------------------------------------
__global__ __launch_bounds__(256) void trans_kernel(
    const float* __restrict__ w, bf16* __restrict__ wt) {
  __shared__ __align__(16) float tile[64][65];
  const int bt = blockIdx.x;
  const int e = bt & 7;
  const int j = bt >> 3;
  const int i0 = (j >> 4) * 64;
  const int o0 = (j & 15) * 64;
  const int tid = threadIdx.x;
  const int c4 = (tid & 15) * 4;
  const int r = tid >> 4;

  const float* src = w + ((size_t)e * DIN + i0) * DOUT + o0;
#pragma unroll
  for (int rr = r; rr < 64; rr += 16) {
    const floatx4 v = *(const floatx4*)(src + (size_t)rr * DOUT + c4);
    tile[rr][c4] = v[0]; tile[rr][c4 + 1] = v[1];
    tile[rr][c4 + 2] = v[2]; tile[rr][c4 + 3] = v[3];
  }
  __syncthreads();
  bf16* dst = wt + ((size_t)e * DOUT + o0) * DIN + i0;
#pragma unroll
  for (int rr = r; rr < 64; rr += 16) {
    union { bf16 b[4]; uint64_t u; } cv;
#pragma unroll
    for (int jj = 0; jj < 4; ++jj) cv.b[jj] = (bf16)tile[c4 + jj][rr];
    *(uint64_t*)(dst + (size_t)rr * DIN + c4) = cv.u;
  }
}

// ---------------------------------------------------------------------------
// Fused MoE GEMM — VERBATIM the R8 kernel (measured 135.1us, MfmaUtil 45.7%,
// conflicts 0, VGPR 108, no spill; best of 7 schedule variants; R12/R13/R14
// counted-vmcnt/deeper-pipeline attempts all regressed or spilled).
// BK=64, LDS dbuf 2x(A+B)=64KB (2 blocks/CU), ONE __syncthreads per K-tile;
// stage of tile t+1 issued between the two 16-MFMA clusters of tile t,
// drained at the boundary. Frag ds_reads issue BEFORE the async LDS stores.
// Swizzle: unit u=tid+256j -> row=u>>3 (=srow+32j, row&7 invariant),
// phys chunk c=u&7 holds global col-group c^(row&7); reader wants group
// kk*4+lq at phys (kk*4+lq)^(lr&7) since row&7==lr&7 for frag rows.
// ---------------------------------------------------------------------------
__global__ __launch_bounds__(256, 2) void moe_gemm(
    const bf16* __restrict__ xb, const bf16* __restrict__ wt,
    const float* __restrict__ g, float* __restrict__ out) {
  __shared__ __align__(16) bf16 As[2][128 * 64];  // 2 x 16KB
  __shared__ __align__(16) bf16 Bs[2][128 * 64];  // 2 x 16KB

  const int tid = threadIdx.x;
  // XCD swizzle on 512 blocks: c = idx&7 (XCD), jj = idx>>3 in [0,64).
  const int c = blockIdx.x & 7;
  const int jj = blockIdx.x >> 3;
  const int bm = (c >> 1) * 16 + (jj & 15);   // 0..63
  const int bn = (c & 1) * 4 + (jj >> 4);     // 0..7
  const int lane = tid & 63;
  const int wave = tid >> 6;
  const int wm = wave >> 1, wn = wave & 1;
  const int lr = lane & 15, lq = lane >> 4;

  // staging: rows have 8 16B-units (64 cols). srow in 0..31, +32 per pass.
  const int srow = tid >> 3;
  const int scol = (((tid & 7) ^ (srow & 7)) << 3);
  const int kx = lr & 7;

  const bf16* const agp = xb + (size_t)(bm * 128 + srow) * DIN + scol;
  const bf16* const bgp = wt + (size_t)(bn * 128 + srow) * DIN + scol;

  const floatx4 fzero = {0.f, 0.f, 0.f, 0.f};
  floatx4 accF[4][4], accE[4][4];
#pragma unroll
  for (int im = 0; im < 4; ++im)
#pragma unroll
    for (int in = 0; in < 4; ++in) { accF[im][in] = fzero; accE[im][in] = fzero; }

  const int tok0 = bm * 128 + wm * 64;

  // prologue: stage tile 0 (e=0, k0=0) into buffer 0
  {
    bf16* const alp = &As[0][tid * 8];
    bf16* const blp = &Bs[0][tid * 8];
#pragma unroll
    for (int j = 0; j < 4; ++j)
      async16(agp + (size_t)(32 * j) * DIN, alp + j * 2048);
#pragma unroll
    for (int j = 0; j < 4; ++j)
      async16(bgp + (size_t)(32 * j) * DIN, blp + j * 2048);
  }
  __syncthreads();

  // 128 flattened K-tiles: t = e*16 + kt, k0 = kt*64.
  for (int t = 0; t < 128; ++t) {
    const int cur = t & 1;
    const bf16* const Ab = &As[cur][0];
    const bf16* const Bb = &Bs[cur][0];

    // 1) fragment reads for both kk halves (before any LDS stores)
    bf16x8 av[2][4], bv[2][4];
#pragma unroll
    for (int kk = 0; kk < 2; ++kk) {
      const int kg = ((kk * 4 + lq) ^ kx) << 3;
#pragma unroll
      for (int im = 0; im < 4; ++im)
        av[kk][im] = *(const bf16x8*)(Ab + (wm * 64 + im * 16 + lr) * 64 + kg);
#pragma unroll
      for (int in = 0; in < 4; ++in)
        bv[kk][in] = *(const bf16x8*)(Bb + (wn * 64 + in * 16 + lr) * 64 + kg);
    }

    // 2) stage tile t+1 (A half), overlapped with kk=0 MFMA
    const int t1 = t + 1;
    bf16* const alp = &As[cur ^ 1][tid * 8];
    bf16* const blp = &Bs[cur ^ 1][tid * 8];
    const size_t koff = (size_t)((t1 & 15) << 6);
    if (t1 < 128) {
#pragma unroll
      for (int j = 0; j < 4; ++j)
        async16(agp + koff + (size_t)(32 * j) * DIN, alp + j * 2048);
    }

    __builtin_amdgcn_s_setprio(1);
#pragma unroll
    for (int im = 0; im < 4; ++im)
#pragma unroll
      for (int in = 0; in < 4; ++in)
        accE[im][in] = __builtin_amdgcn_mfma_f32_16x16x32_bf16(
            av[0][im], bv[0][in], accE[im][in], 0, 0, 0);
    __builtin_amdgcn_s_setprio(0);

    // 3) stage tile t+1 (B half), overlapped with kk=1 MFMA
    if (t1 < 128) {
      const bf16* const bsrc = bgp + ((size_t)(t1 >> 4) << 20) + koff;
#pragma unroll
      for (int j = 0; j < 4; ++j)
        async16(bsrc + (size_t)(32 * j) * DIN, blp + j * 2048);
    }

    __builtin_amdgcn_s_setprio(1);
#pragma unroll
    for (int im = 0; im < 4; ++im)
#pragma unroll
      for (int in = 0; in < 4; ++in)
        accE[im][in] = __builtin_amdgcn_mfma_f32_16x16x32_bf16(
            av[1][im], bv[1][in], accE[im][in], 0, 0, 0);
    __builtin_amdgcn_s_setprio(0);

    // 4) expert boundary: fold accE into accF with gate weights
    if ((t & 15) == 15) {
      const int e = t >> 4;
#pragma unroll
      for (int im = 0; im < 4; ++im) {
        float gv[4];
#pragma unroll
        for (int r = 0; r < 4; ++r)
          gv[r] = g[(size_t)(tok0 + im * 16 + lq * 4 + r) * NE + e];
#pragma unroll
        for (int in = 0; in < 4; ++in)
#pragma unroll
          for (int r = 0; r < 4; ++r) {
            accF[im][in][r] += gv[r] * accE[im][in][r];
            accE[im][in][r] = 0.f;
          }
      }
    }

    // 5) boundary: vmcnt(0)+lgkmcnt(0)+barrier — tile t+1 resident after this
    __syncthreads();
  }

#pragma unroll
  for (int im = 0; im < 4; ++im)
#pragma unroll
    for (int in = 0; in < 4; ++in) {
      const int col = bn * 128 + wn * 64 + in * 16 + lr;
#pragma unroll
      for (int r = 0; r < 4; ++r)
        out[(size_t)(tok0 + im * 16 + lq * 4 + r) * DOUT + col] =
            accF[im][in][r];
    }
}

// ---------------------------------------------------------------------------
extern "C" void kernel_launch(void* const* d_in, const int* in_sizes, int n_in,
                              void* d_out, int out_size, void* d_ws,
                              size_t ws_size, hipStream_t stream) {
  const float* x  = (const float*)d_in[0];
  const float* gw = (const float*)d_in[1];
  const float* gb = (const float*)d_in[2];
  const float* w  = (const float*)d_in[3];
  float* out = (float*)d_out;

  char* ws = (char*)d_ws;
  float* g  = (float*)ws;
  bf16* xb  = (bf16*)(ws + 262144);
  bf16* wt  = (bf16*)(ws + 262144 + (size_t)TOKENS * DIN * 2);

  trans_kernel<<<2048, 256, 0, stream>>>(w, wt);
  gate_kernel<<<512, 256, 0, stream>>>(x, gw, gb, g, xb);
  moe_gemm<<<512, 256, 0, stream>>>(xb, wt, g, out);
}

// Round 10
// 232.956 us; speedup vs baseline: 2.8495x; 1.0123x over previous
//
#include <hip/hip_runtime.h>
#include <hip/hip_bf16.h>
#include <cstdint>

#define TOKENS 8192
#define DIN 1024
#define DOUT 1024
#define NE 8

typedef __bf16 bf16;
typedef __attribute__((ext_vector_type(8))) __bf16 bf16x8;
typedef __attribute__((ext_vector_type(4))) float floatx4;

// async global->LDS, 16B per lane. LDS dest must be wave-uniform base + lane*16.
__device__ __forceinline__ void async16(const void* gptr, void* lptr) {
  __builtin_amdgcn_global_load_lds(
      (const __attribute__((address_space(1))) void*)gptr,
      (__attribute__((address_space(3))) void*)lptr,
      16, 0, 0);
}

// ---------------------------------------------------------------------------
// R16 prep: gate+trans fused into ONE kernel (one launch fewer; gate and
// trans blocks run concurrently — as separate kernels they serialize on the
// stream). Static LDS = 32KB, shared by both paths (trans tile aliases gws).
// Blocks [0,512): R15-verified gate — softmax + x -> ROW-MAJOR bf16 xb
// written directly from registers (no xtile staging).
// Blocks [512,2560): R15-verified trans — w[e][i][o] -> wt[e][o][i] bf16,
// XCD-contiguous mapping (e = bt&7 = XCD under %8 round-robin).
// ---------------------------------------------------------------------------
__global__ __launch_bounds__(256) void prep_kernel(
    const float* __restrict__ x, const float* __restrict__ gw,
    const float* __restrict__ gb, float* __restrict__ g,
    bf16* __restrict__ xb, const float* __restrict__ w,
    bf16* __restrict__ wt) {
  __shared__ __align__(16) float smem[NE * DIN];  // 32 KB

  const int tid = threadIdx.x;
  if (blockIdx.x < 512) {
    // ---------------- gate path ----------------
#pragma unroll
    for (int k = 0; k < 8; ++k) {
      const int base = (k * 256 + tid) * 4;
      const floatx4 v = *(const floatx4*)(gw + base);
#pragma unroll
      for (int m = 0; m < 4; ++m) {
        const int j = base + m;
        smem[(j & 7) * DIN + (j >> 3)] = v[m];
      }
    }
    __syncthreads();

    const int lane = tid & 63;
    const int wave = tid >> 6;
#pragma unroll
    for (int tt = 0; tt < 4; ++tt) {
      const int t = blockIdx.x * 16 + wave * 4 + tt;
      const float* xr = x + (size_t)t * DIN;
      bf16* xbr = xb + (size_t)t * DIN;

      float acc[NE];
#pragma unroll
      for (int e = 0; e < NE; ++e) acc[e] = 0.f;

#pragma unroll
      for (int it = 0; it < 4; ++it) {
        const int i = it * 256 + lane * 4;
        const floatx4 xv = *(const floatx4*)(xr + i);
        union { bf16 b[4]; uint64_t u; } cv;
#pragma unroll
        for (int m = 0; m < 4; ++m) cv.b[m] = (bf16)xv[m];
        *(uint64_t*)(xbr + i) = cv.u;
#pragma unroll
        for (int e = 0; e < NE; ++e) {
          const floatx4 wv = *(const floatx4*)(smem + e * DIN + i);
          acc[e] += xv[0] * wv[0] + xv[1] * wv[1] + xv[2] * wv[2] + xv[3] * wv[3];
        }
      }
#pragma unroll
      for (int e = 0; e < NE; ++e)
#pragma unroll
        for (int off = 32; off > 0; off >>= 1)
          acc[e] += __shfl_xor(acc[e], off, 64);

      float lg[NE];
      float mx = -3.0e38f;
#pragma unroll
      for (int e = 0; e < NE; ++e) { lg[e] = acc[e] + gb[e]; mx = fmaxf(mx, lg[e]); }
      float s = 0.f;
#pragma unroll
      for (int e = 0; e < NE; ++e) { lg[e] = __expf(lg[e] - mx); s += lg[e]; }
      const float inv = 1.f / s;
      if (lane == 0) {
        floatx4 o0, o1;
#pragma unroll
        for (int e = 0; e < 4; ++e) { o0[e] = lg[e] * inv; o1[e] = lg[e + 4] * inv; }
        *(floatx4*)(g + (size_t)t * NE) = o0;
        *(floatx4*)(g + (size_t)t * NE + 4) = o1;
      }
    }
  } else {
    // ---------------- trans path ----------------
    float (*tile)[65] = (float(*)[65])smem;   // 16.6 KB, aliases gws region
    const int bt = blockIdx.x - 512;
    const int e = bt & 7;                     // = XCD under %8 round-robin
    const int j = bt >> 3;
    const int i0 = (j >> 4) * 64;
    const int o0 = (j & 15) * 64;
    const int c4 = (tid & 15) * 4;
    const int r = tid >> 4;

    const float* src = w + ((size_t)e * DIN + i0) * DOUT + o0;
#pragma unroll
    for (int rr = r; rr < 64; rr += 16) {
      const floatx4 v = *(const floatx4*)(src + (size_t)rr * DOUT + c4);
      tile[rr][c4] = v[0]; tile[rr][c4 + 1] = v[1];
      tile[rr][c4 + 2] = v[2]; tile[rr][c4 + 3] = v[3];
    }
    __syncthreads();
    bf16* dst = wt + ((size_t)e * DOUT + o0) * DIN + i0;
#pragma unroll
    for (int rr = r; rr < 64; rr += 16) {
      union { bf16 b[4]; uint64_t u; } cv;
#pragma unroll
      for (int jj = 0; jj < 4; ++jj) cv.b[jj] = (bf16)tile[c4 + jj][rr];
      *(uint64_t*)(dst + (size_t)rr * DIN + c4) = cv.u;
    }
  }
}

// ---------------------------------------------------------------------------
// Fused MoE GEMM — VERBATIM R8/R15 kernel (twice-measured 129.6-135.1us,
// MfmaUtil 45.7-47.1%, conflicts 0, VGPR 108, no spill; best of 7 schedule
// variants — R12/R13/R14 counted-vmcnt/deeper pipelines all regressed or
// spilled at this register envelope).
// BK=64, LDS dbuf 2x(A+B)=64KB (2 blocks/CU), ONE __syncthreads per K-tile;
// stage of tile t+1 issued between the two 16-MFMA clusters of tile t,
// drained at the boundary. Frag ds_reads issue BEFORE the async LDS stores.
// Swizzle: unit u=tid+256j -> row=u>>3 (=srow+32j, row&7 invariant),
// phys chunk c=u&7 holds global col-group c^(row&7); reader wants group
// kk*4+lq at phys (kk*4+lq)^(lr&7) since row&7==lr&7 for frag rows.
// ---------------------------------------------------------------------------
__global__ __launch_bounds__(256, 2) void moe_gemm(
    const bf16* __restrict__ xb, const bf16* __restrict__ wt,
    const float* __restrict__ g, float* __restrict__ out) {
  __shared__ __align__(16) bf16 As[2][128 * 64];  // 2 x 16KB
  __shared__ __align__(16) bf16 Bs[2][128 * 64];  // 2 x 16KB

  const int tid = threadIdx.x;
  // XCD swizzle on 512 blocks: c = idx&7 (XCD), jj = idx>>3 in [0,64).
  const int c = blockIdx.x & 7;
  const int jj = blockIdx.x >> 3;
  const int bm = (c >> 1) * 16 + (jj & 15);   // 0..63
  const int bn = (c & 1) * 4 + (jj >> 4);     // 0..7
  const int lane = tid & 63;
  const int wave = tid >> 6;
  const int wm = wave >> 1, wn = wave & 1;
  const int lr = lane & 15, lq = lane >> 4;

  // staging: rows have 8 16B-units (64 cols). srow in 0..31, +32 per pass.
  const int srow = tid >> 3;
  const int scol = (((tid & 7) ^ (srow & 7)) << 3);
  const int kx = lr & 7;

  const bf16* const agp = xb + (size_t)(bm * 128 + srow) * DIN + scol;
  const bf16* const bgp = wt + (size_t)(bn * 128 + srow) * DIN + scol;

  const floatx4 fzero = {0.f, 0.f, 0.f, 0.f};
  floatx4 accF[4][4], accE[4][4];
#pragma unroll
  for (int im = 0; im < 4; ++im)
#pragma unroll
    for (int in = 0; in < 4; ++in) { accF[im][in] = fzero; accE[im][in] = fzero; }

  const int tok0 = bm * 128 + wm * 64;

  // prologue: stage tile 0 (e=0, k0=0) into buffer 0
  {
    bf16* const alp = &As[0][tid * 8];
    bf16* const blp = &Bs[0][tid * 8];
#pragma unroll
    for (int j = 0; j < 4; ++j)
      async16(agp + (size_t)(32 * j) * DIN, alp + j * 2048);
#pragma unroll
    for (int j = 0; j < 4; ++j)
      async16(bgp + (size_t)(32 * j) * DIN, blp + j * 2048);
  }
  __syncthreads();

  // 128 flattened K-tiles: t = e*16 + kt, k0 = kt*64.
  for (int t = 0; t < 128; ++t) {
    const int cur = t & 1;
    const bf16* const Ab = &As[cur][0];
    const bf16* const Bb = &Bs[cur][0];

    // 1) fragment reads for both kk halves (before any LDS stores)
    bf16x8 av[2][4], bv[2][4];
#pragma unroll
    for (int kk = 0; kk < 2; ++kk) {
      const int kg = ((kk * 4 + lq) ^ kx) << 3;
#pragma unroll
      for (int im = 0; im < 4; ++im)
        av[kk][im] = *(const bf16x8*)(Ab + (wm * 64 + im * 16 + lr) * 64 + kg);
#pragma unroll
      for (int in = 0; in < 4; ++in)
        bv[kk][in] = *(const bf16x8*)(Bb + (wn * 64 + in * 16 + lr) * 64 + kg);
    }

    // 2) stage tile t+1 (A half), overlapped with kk=0 MFMA
    const int t1 = t + 1;
    bf16* const alp = &As[cur ^ 1][tid * 8];
    bf16* const blp = &Bs[cur ^ 1][tid * 8];
    const size_t koff = (size_t)((t1 & 15) << 6);
    if (t1 < 128) {
#pragma unroll
      for (int j = 0; j < 4; ++j)
        async16(agp + koff + (size_t)(32 * j) * DIN, alp + j * 2048);
    }

    __builtin_amdgcn_s_setprio(1);
#pragma unroll
    for (int im = 0; im < 4; ++im)
#pragma unroll
      for (int in = 0; in < 4; ++in)
        accE[im][in] = __builtin_amdgcn_mfma_f32_16x16x32_bf16(
            av[0][im], bv[0][in], accE[im][in], 0, 0, 0);
    __builtin_amdgcn_s_setprio(0);

    // 3) stage tile t+1 (B half), overlapped with kk=1 MFMA
    if (t1 < 128) {
      const bf16* const bsrc = bgp + ((size_t)(t1 >> 4) << 20) + koff;
#pragma unroll
      for (int j = 0; j < 4; ++j)
        async16(bsrc + (size_t)(32 * j) * DIN, blp + j * 2048);
    }

    __builtin_amdgcn_s_setprio(1);
#pragma unroll
    for (int im = 0; im < 4; ++im)
#pragma unroll
      for (int in = 0; in < 4; ++in)
        accE[im][in] = __builtin_amdgcn_mfma_f32_16x16x32_bf16(
            av[1][im], bv[1][in], accE[im][in], 0, 0, 0);
    __builtin_amdgcn_s_setprio(0);

    // 4) expert boundary: fold accE into accF with gate weights
    if ((t & 15) == 15) {
      const int e = t >> 4;
#pragma unroll
      for (int im = 0; im < 4; ++im) {
        float gv[4];
#pragma unroll
        for (int r = 0; r < 4; ++r)
          gv[r] = g[(size_t)(tok0 + im * 16 + lq * 4 + r) * NE + e];
#pragma unroll
        for (int in = 0; in < 4; ++in)
#pragma unroll
          for (int r = 0; r < 4; ++r) {
            accF[im][in][r] += gv[r] * accE[im][in][r];
            accE[im][in][r] = 0.f;
          }
      }
    }

    // 5) boundary: vmcnt(0)+lgkmcnt(0)+barrier — tile t+1 resident after this
    __syncthreads();
  }

#pragma unroll
  for (int im = 0; im < 4; ++im)
#pragma unroll
    for (int in = 0; in < 4; ++in) {
      const int col = bn * 128 + wn * 64 + in * 16 + lr;
#pragma unroll
      for (int r = 0; r < 4; ++r)
        out[(size_t)(tok0 + im * 16 + lq * 4 + r) * DOUT + col] =
            accF[im][in][r];
    }
}

// ---------------------------------------------------------------------------
extern "C" void kernel_launch(void* const* d_in, const int* in_sizes, int n_in,
                              void* d_out, int out_size, void* d_ws,
                              size_t ws_size, hipStream_t stream) {
  const float* x  = (const float*)d_in[0];
  const float* gw = (const float*)d_in[1];
  const float* gb = (const float*)d_in[2];
  const float* w  = (const float*)d_in[3];
  float* out = (float*)d_out;

  char* ws = (char*)d_ws;
  float* g  = (float*)ws;
  bf16* xb  = (bf16*)(ws + 262144);
  bf16* wt  = (bf16*)(ws + 262144 + (size_t)TOKENS * DIN * 2);

  prep_kernel<<<2560, 256, 0, stream>>>(x, gw, gb, g, xb, w, wt);
  moe_gemm<<<512, 256, 0, stream>>>(xb, wt, g, out);
}

// Round 11
// 230.702 us; speedup vs baseline: 2.8774x; 1.0098x over previous
//
#include <hip/hip_runtime.h>
#include <hip/hip_bf16.h>
#include <cstdint>

#define TOKENS 8192
#define DIN 1024
#define DOUT 1024
#define NE 8

typedef __bf16 bf16;
typedef __attribute__((ext_vector_type(8))) __bf16 bf16x8;
typedef __attribute__((ext_vector_type(4))) float floatx4;

// async global->LDS, 16B per lane. LDS dest must be wave-uniform base + lane*16.
__device__ __forceinline__ void async16(const void* gptr, void* lptr) {
  __builtin_amdgcn_global_load_lds(
      (const __attribute__((address_space(1))) void*)gptr,
      (__attribute__((address_space(3))) void*)lptr,
      16, 0, 0);
}

// ---------------------------------------------------------------------------
// Prep (byte-identical to R16's measured version): gate+trans fused.
// Blocks [0,512): gate softmax + x -> ROW-MAJOR bf16 xb from registers.
// Blocks [512,2560): w[e][i][o] -> wt[e][o][i] bf16, XCD-contiguous mapping.
// ---------------------------------------------------------------------------
__global__ __launch_bounds__(256) void prep_kernel(
    const float* __restrict__ x, const float* __restrict__ gw,
    const float* __restrict__ gb, float* __restrict__ g,
    bf16* __restrict__ xb, const float* __restrict__ w,
    bf16* __restrict__ wt) {
  __shared__ __align__(16) float smem[NE * DIN];  // 32 KB

  const int tid = threadIdx.x;
  if (blockIdx.x < 512) {
#pragma unroll
    for (int k = 0; k < 8; ++k) {
      const int base = (k * 256 + tid) * 4;
      const floatx4 v = *(const floatx4*)(gw + base);
#pragma unroll
      for (int m = 0; m < 4; ++m) {
        const int j = base + m;
        smem[(j & 7) * DIN + (j >> 3)] = v[m];
      }
    }
    __syncthreads();

    const int lane = tid & 63;
    const int wave = tid >> 6;
#pragma unroll
    for (int tt = 0; tt < 4; ++tt) {
      const int t = blockIdx.x * 16 + wave * 4 + tt;
      const float* xr = x + (size_t)t * DIN;
      bf16* xbr = xb + (size_t)t * DIN;

      float acc[NE];
#pragma unroll
      for (int e = 0; e < NE; ++e) acc[e] = 0.f;

#pragma unroll
      for (int it = 0; it < 4; ++it) {
        const int i = it * 256 + lane * 4;
        const floatx4 xv = *(const floatx4*)(xr + i);
        union { bf16 b[4]; uint64_t u; } cv;
#pragma unroll
        for (int m = 0; m < 4; ++m) cv.b[m] = (bf16)xv[m];
        *(uint64_t*)(xbr + i) = cv.u;
#pragma unroll
        for (int e = 0; e < NE; ++e) {
          const floatx4 wv = *(const floatx4*)(smem + e * DIN + i);
          acc[e] += xv[0] * wv[0] + xv[1] * wv[1] + xv[2] * wv[2] + xv[3] * wv[3];
        }
      }
#pragma unroll
      for (int e = 0; e < NE; ++e)
#pragma unroll
        for (int off = 32; off > 0; off >>= 1)
          acc[e] += __shfl_xor(acc[e], off, 64);

      float lg[NE];
      float mx = -3.0e38f;
#pragma unroll
      for (int e = 0; e < NE; ++e) { lg[e] = acc[e] + gb[e]; mx = fmaxf(mx, lg[e]); }
      float s = 0.f;
#pragma unroll
      for (int e = 0; e < NE; ++e) { lg[e] = __expf(lg[e] - mx); s += lg[e]; }
      const float inv = 1.f / s;
      if (lane == 0) {
        floatx4 o0, o1;
#pragma unroll
        for (int e = 0; e < 4; ++e) { o0[e] = lg[e] * inv; o1[e] = lg[e + 4] * inv; }
        *(floatx4*)(g + (size_t)t * NE) = o0;
        *(floatx4*)(g + (size_t)t * NE + 4) = o1;
      }
    }
  } else {
    float (*tile)[65] = (float(*)[65])smem;
    const int bt = blockIdx.x - 512;
    const int e = bt & 7;
    const int j = bt >> 3;
    const int i0 = (j >> 4) * 64;
    const int o0 = (j & 15) * 64;
    const int c4 = (tid & 15) * 4;
    const int r = tid >> 4;

    const float* src = w + ((size_t)e * DIN + i0) * DOUT + o0;
#pragma unroll
    for (int rr = r; rr < 64; rr += 16) {
      const floatx4 v = *(const floatx4*)(src + (size_t)rr * DOUT + c4);
      tile[rr][c4] = v[0]; tile[rr][c4 + 1] = v[1];
      tile[rr][c4 + 2] = v[2]; tile[rr][c4 + 3] = v[3];
    }
    __syncthreads();
    bf16* dst = wt + ((size_t)e * DOUT + o0) * DIN + i0;
#pragma unroll
    for (int rr = r; rr < 64; rr += 16) {
      union { bf16 b[4]; uint64_t u; } cv;
#pragma unroll
      for (int jj = 0; jj < 4; ++jj) cv.b[jj] = (bf16)tile[c4 + jj][rr];
      *(uint64_t*)(dst + (size_t)rr * DIN + c4) = cv.u;
    }
  }
}

// ---------------------------------------------------------------------------
// Fused MoE GEMM, R17: kt-outer / e-inner with A-fragments held in registers.
// R8 structure was LDS-pipe-bound (model: LDS 2048 cyc > MFMA 1242; wall
// 2512) with A-frags re-read from LDS per expert (8x redundant). Linearity
// (out = sum_kt sum_e g_e * (A_kt B_e,kt)) lets the gate fold act on PARTIAL
// products, legalizing kt-outer: body s = kt*8+e reads av ONCE per kt (8
// ds_read_b128, held in 32 VGPR across 8 bodies), computes accE = A_kt*B_ekt
// (16 MFMA from zero-C + 16 accumulate), folds accF += gv*accE per body.
// gv from a 4KB LDS table gT[e][tok] (broadcast b128 reads, conflict-free).
// A staged once per kt (amortized 2KB/body). New LDS model ~1290 cyc ~=
// MFMA 1242 => MFMA-bound. Sync skeleton/swizzle/frag-math/epilogue are the
// thrice-verified R8 pattern. LDS 68KB -> still 2 blocks/CU.
// ---------------------------------------------------------------------------
__global__ __launch_bounds__(256, 2) void moe_gemm(
    const bf16* __restrict__ xb, const bf16* __restrict__ wt,
    const float* __restrict__ g, float* __restrict__ out) {
  __shared__ __align__(16) bf16 As[2][128 * 64];  // 2 x 16KB
  __shared__ __align__(16) bf16 Bs[2][128 * 64];  // 2 x 16KB
  __shared__ __align__(16) float gT[NE * 128];    // 4KB: gT[e][tok_local]

  const int tid = threadIdx.x;
  // XCD swizzle (verified R7): per-XCD chunk = 16 bm x 4 bn.
  const int c = blockIdx.x & 7;
  const int jj = blockIdx.x >> 3;
  const int bm = (c >> 1) * 16 + (jj & 15);   // 0..63
  const int bn = (c & 1) * 4 + (jj >> 4);     // 0..7
  const int lane = tid & 63;
  const int wave = tid >> 6;
  const int wm = wave >> 1, wn = wave & 1;
  const int lr = lane & 15, lq = lane >> 4;

  // staging (verified R8): srow 0..31 (+32/pass), swizzled col.
  const int srow = tid >> 3;
  const int scol = (((tid & 7) ^ (srow & 7)) << 3);
  const int kx = lr & 7;

  const bf16* const agp = xb + (size_t)(bm * 128 + srow) * DIN + scol;
  const bf16* const bgp = wt + (size_t)(bn * 128 + srow) * DIN + scol;

  const floatx4 fzero = {0.f, 0.f, 0.f, 0.f};
  floatx4 accF[4][4];
#pragma unroll
  for (int im = 0; im < 4; ++im)
#pragma unroll
    for (int in = 0; in < 4; ++in) accF[im][in] = fzero;

  const int tok0 = bm * 128 + wm * 64;

  // prologue: fill gT (transpose 128x8 -> [e][tok]), stage A(0) and B(0,0)
  {
    const int tok = tid >> 1, eh = (tid & 1) * 4;
    const floatx4 gv4 = *(const floatx4*)(g + (size_t)(bm * 128 + tok) * NE + eh);
#pragma unroll
    for (int m = 0; m < 4; ++m) gT[(eh + m) * 128 + tok] = gv4[m];
  }
  {
    bf16* const alp = &As[0][tid * 8];
    bf16* const blp = &Bs[0][tid * 8];
#pragma unroll
    for (int j = 0; j < 4; ++j)
      async16(agp + (size_t)(32 * j) * DIN, alp + j * 2048);
#pragma unroll
    for (int j = 0; j < 4; ++j)
      async16(bgp + (size_t)(32 * j) * DIN, blp + j * 2048);
  }
  __syncthreads();

  bf16x8 av[2][4];  // A-fragments for current kt, held across 8 e-bodies

  // 128 bodies: s = kt*8 + e
  for (int s = 0; s < 128; ++s) {
    const int kt = s >> 3;
    const int e = s & 7;
    const int cur = s & 1;

    // 1) fragment reads (before any LDS stores). av only at e==0.
    if (e == 0) {
      const bf16* const Ab = &As[kt & 1][0];
#pragma unroll
      for (int kk = 0; kk < 2; ++kk) {
        const int kg = ((kk * 4 + lq) ^ kx) << 3;
#pragma unroll
        for (int im = 0; im < 4; ++im)
          av[kk][im] = *(const bf16x8*)(Ab + (wm * 64 + im * 16 + lr) * 64 + kg);
      }
    }
    const bf16* const Bb = &Bs[cur][0];
    bf16x8 bv[2][4];
#pragma unroll
    for (int kk = 0; kk < 2; ++kk) {
      const int kg = ((kk * 4 + lq) ^ kx) << 3;
#pragma unroll
      for (int in = 0; in < 4; ++in)
        bv[kk][in] = *(const bf16x8*)(Bb + (wn * 64 + in * 16 + lr) * 64 + kg);
    }
    // gate weights for this body's expert (broadcast reads, conflict-free)
    floatx4 gvi[4];
#pragma unroll
    for (int im = 0; im < 4; ++im)
      gvi[im] = *(const floatx4*)(gT + e * 128 + wm * 64 + im * 16 + lq * 4);

    // 2) stage next body's B; at e==0 also stage A(kt+1)
    const int s1 = s + 1;
    if (s1 < 128) {
      const int e1 = s1 & 7, kt1 = s1 >> 3;
      const bf16* const bsrc =
          bgp + ((size_t)e1 << 20) + (size_t)kt1 * 64;
      bf16* const blp = &Bs[cur ^ 1][tid * 8];
#pragma unroll
      for (int j = 0; j < 4; ++j)
        async16(bsrc + (size_t)(32 * j) * DIN, blp + j * 2048);
    }
    if (e == 0 && kt + 1 < 16) {
      bf16* const alp = &As[(kt + 1) & 1][tid * 8];
#pragma unroll
      for (int j = 0; j < 4; ++j)
        async16(agp + (size_t)(kt + 1) * 64 + (size_t)(32 * j) * DIN,
                alp + j * 2048);
    }

    // 3) MFMA: accE = A_kt * B_e,kt (kk=0 from zero-C, kk=1 accumulates)
    floatx4 accE[4][4];
    __builtin_amdgcn_s_setprio(1);
#pragma unroll
    for (int im = 0; im < 4; ++im)
#pragma unroll
      for (int in = 0; in < 4; ++in)
        accE[im][in] = __builtin_amdgcn_mfma_f32_16x16x32_bf16(
            av[0][im], bv[0][in], fzero, 0, 0, 0);
    __builtin_amdgcn_s_setprio(0);
    __builtin_amdgcn_s_setprio(1);
#pragma unroll
    for (int im = 0; im < 4; ++im)
#pragma unroll
      for (int in = 0; in < 4; ++in)
        accE[im][in] = __builtin_amdgcn_mfma_f32_16x16x32_bf16(
            av[1][im], bv[1][in], accE[im][in], 0, 0, 0);
    __builtin_amdgcn_s_setprio(0);

    // 4) fold partial product with gate weight
#pragma unroll
    for (int im = 0; im < 4; ++im)
#pragma unroll
      for (int in = 0; in < 4; ++in)
#pragma unroll
        for (int r = 0; r < 4; ++r)
          accF[im][in][r] += gvi[im][r] * accE[im][in][r];

    // 5) boundary: drains staging — next body's B (and A at kt edges) resident
    __syncthreads();
  }

#pragma unroll
  for (int im = 0; im < 4; ++im)
#pragma unroll
    for (int in = 0; in < 4; ++in) {
      const int col = bn * 128 + wn * 64 + in * 16 + lr;
#pragma unroll
      for (int r = 0; r < 4; ++r)
        out[(size_t)(tok0 + im * 16 + lq * 4 + r) * DOUT + col] =
            accF[im][in][r];
    }
}

// ---------------------------------------------------------------------------
extern "C" void kernel_launch(void* const* d_in, const int* in_sizes, int n_in,
                              void* d_out, int out_size, void* d_ws,
                              size_t ws_size, hipStream_t stream) {
  const float* x  = (const float*)d_in[0];
  const float* gw = (const float*)d_in[1];
  const float* gb = (const float*)d_in[2];
  const float* w  = (const float*)d_in[3];
  float* out = (float*)d_out;

  char* ws = (char*)d_ws;
  float* g  = (float*)ws;
  bf16* xb  = (bf16*)(ws + 262144);
  bf16* wt  = (bf16*)(ws + 262144 + (size_t)TOKENS * DIN * 2);

  prep_kernel<<<2560, 256, 0, stream>>>(x, gw, gb, g, xb, w, wt);
  moe_gemm<<<512, 256, 0, stream>>>(xb, wt, g, out);
}